// Round 6
// baseline (255.324 us; speedup 1.0000x reference)
//
#include <hip/hip_runtime.h>
#include <cstdint>

// B=4, S=2048, D=1024.  M_qkv = B*S = 8192.
// ws layout (bytes):
//   x_bf   @ 0         : 16,777,216   bf16 [8192][1024]   (dead after proj)
//   gsum   @ 0         :    524,288   f32 [8192][16] row-sum partials (overlaps
//                                     dead x_bf; written by score, read by PV)
//   w_bf   @ 16777216  :  6,291,456   bf16 Wq,Wk,Wv each [1024][1024]
//   Q      @ 23068672  : 16,777,216   bf16 [8192][1024]
//   K      @ 39845888  : 16,777,216
//   Vt     @ 56623104  : 16,777,216   bf16 [1024][8192], col = b*2048+s
//   P~     @ 73400320  : 33,554,432   bf16 [4][2048][2048] = exp(s/32), unnorm.
// total ~102 MB

typedef __bf16 bf16x8_t __attribute__((ext_vector_type(8)));
typedef float  f32x4_t  __attribute__((ext_vector_type(4)));

__device__ __forceinline__ uint16_t f2bf(float f) {
    union { float f; uint32_t u; } v; v.f = f;
    return (uint16_t)((v.u + 0x7fffu + ((v.u >> 16) & 1u)) >> 16);  // RNE
}

__device__ __forceinline__ void gload_lds16(const uint16_t* g, uint16_t* lds) {
    __builtin_amdgcn_global_load_lds(
        (const __attribute__((address_space(1))) void*)g,
        (__attribute__((address_space(3))) void*)lds, 16, 0, 0);
}

// ---------------------------------------------------------------------------
// QKV projections, ONE dispatch, grid (64, 8, 3), all 128x128/BK=64 tiles.
//   z=0: Q  = x @ Wq^T + bq   m0=bx*128 (8192), n0=by*128 (1024), col-bias
//   z=1: K  = x @ Wk^T + bk   same mapping
//   z=2: Vt = Wv @ x^T + bv   m0=by*128 (1024), n0=bx*128 (8192), row-bias
// bx sweeps x-rows identically for all z (as A for z<2, as B for z=2).
// K-loop body is a VERBATIM copy of gemm_bt's (r5) — deliberately NOT shared
// source, so score/PV codegen cannot be perturbed (r4 lesson).
// ---------------------------------------------------------------------------
__global__ __launch_bounds__(256, 4) void proj_qkv(
    const uint16_t* __restrict__ x_bf, const uint16_t* __restrict__ w_bf,
    const float* __restrict__ bq, const float* __restrict__ bk,
    const float* __restrict__ bv,
    uint16_t* __restrict__ Qb, uint16_t* __restrict__ Kb,
    uint16_t* __restrict__ Vt)
{
    __shared__ uint16_t ldsA[128 * 64];
    __shared__ uint16_t ldsB[128 * 64];

    const int tid  = threadIdx.x;
    const int wave = tid >> 6;
    const int lane = tid & 63;
    const int quad = lane >> 4;
    const int l15  = lane & 15;

    const int z   = blockIdx.z;
    const bool isV = (z == 2);
    const uint16_t* A = isV ? (w_bf + 2 * 1048576) : x_bf;
    const uint16_t* B = isV ? x_bf : (w_bf + z * 1048576);
    uint16_t* C       = (z == 0) ? Qb : (z == 1) ? Kb : Vt;
    const float* bias = (z == 0) ? bq : (z == 1) ? bk : bv;
    const int ldc = isV ? 8192 : 1024;
    const int m0  = (isV ? blockIdx.y : blockIdx.x) * 128;
    const int n0  = (isV ? blockIdx.x : blockIdx.y) * 128;

    const uint16_t* gA[4];
    const uint16_t* gB[4];
    uint16_t* lA[4];
    uint16_t* lB[4];
#pragma unroll
    for (int c = 0; c < 4; ++c) {
        const int s   = (c * 4 + wave) * 64 + lane;
        const int r   = s >> 3;
        const int col = ((s & 7) ^ (r & 7)) * 8;
        gA[c] = A + (long long)(m0 + r) * 1024 + col;
        gB[c] = B + (long long)(n0 + r) * 1024 + col;
        lA[c] = ldsA + (c * 4 + wave) * 512;   // wave-uniform base
        lB[c] = ldsB + (c * 4 + wave) * 512;
    }

    const int m_off = (wave & 1) * 64;
    const int n_off = (wave >> 1) * 64;

    f32x4_t acc[4][4];
#pragma unroll
    for (int i = 0; i < 4; ++i)
#pragma unroll
        for (int j = 0; j < 4; ++j)
            acc[i][j] = f32x4_t{0.f, 0.f, 0.f, 0.f};

    for (int k0 = 0; k0 < 1024; k0 += 64) {
#pragma unroll
        for (int c = 0; c < 4; ++c) gload_lds16(gA[c], lA[c]);
#pragma unroll
        for (int c = 0; c < 4; ++c) gload_lds16(gB[c], lB[c]);
#pragma unroll
        for (int c = 0; c < 4; ++c) { gA[c] += 64; gB[c] += 64; }
        __syncthreads();

#pragma unroll
        for (int t = 0; t < 2; ++t) {
            const int csw = ((t * 4 + quad) ^ (l15 & 7)) * 8;
            bf16x8_t af[4], bfr[4];
#pragma unroll
            for (int i = 0; i < 4; ++i)
                af[i] = *(const bf16x8_t*)(ldsA + (m_off + i * 16 + l15) * 64 + csw);
#pragma unroll
            for (int j = 0; j < 4; ++j)
                bfr[j] = *(const bf16x8_t*)(ldsB + (n_off + j * 16 + l15) * 64 + csw);
#pragma unroll
            for (int i = 0; i < 4; ++i)
#pragma unroll
                for (int j = 0; j < 4; ++j)
                    acc[i][j] = __builtin_amdgcn_mfma_f32_16x16x32_bf16(af[i], bfr[j], acc[i][j], 0, 0, 0);
        }
        __syncthreads();
    }

#pragma unroll
    for (int i = 0; i < 4; ++i) {
        const int mb = m0 + m_off + i * 16 + quad * 4;
        float rb[4];
        if (isV) {
#pragma unroll
            for (int r = 0; r < 4; ++r) rb[r] = bias[mb + r];
        }
#pragma unroll
        for (int j = 0; j < 4; ++j) {
            const int n = n0 + n_off + j * 16 + l15;
            const float cb = isV ? 0.f : bias[n];
#pragma unroll
            for (int r = 0; r < 4; ++r) {
                const float v = acc[i][j][r] + (isV ? rb[r] : cb);
                C[(long long)(mb + r) * ldc + n] = f2bf(v);
            }
        }
    }
}

// ---------------------------------------------------------------------------
// Generic 128x128/BK=64 B^T GEMM (r5 source, UNchanged) for score and PV.
// EPI: 3 = exp(acc*alpha) bf16 out + partial row sums -> gsum[m*16 + nblk]
//      4 = acc * (1/sum16(gsum_row)) fp32 out (PV)
// ---------------------------------------------------------------------------
template <int EPI, typename OutT>
__global__ __launch_bounds__(256, 4) void gemm_bt(
    const uint16_t* __restrict__ A, int lda, long long sAz,
    const uint16_t* __restrict__ B, int ldb, long long sBz,
    OutT* __restrict__ C, int ldc, long long sCz,
    float* __restrict__ gsum, int K, float alpha)
{
    __shared__ uint16_t ldsA[128 * 64];
    __shared__ uint16_t ldsB[128 * 64];
    __shared__ float inv_denom[128];

    const int tid  = threadIdx.x;
    const int wave = tid >> 6;
    const int lane = tid & 63;
    const int quad = lane >> 4;
    const int l15  = lane & 15;
    const int z    = blockIdx.z;

    A += (long long)z * sAz;
    B += (long long)z * sBz;
    C += (long long)z * sCz;

    const int m0 = blockIdx.x * 128;
    const int n0 = blockIdx.y * 128;

    if (EPI == 4) {
        if (tid < 128) {
            const float* gp = gsum + (long long)z * 32768 + (m0 + tid) * 16;
            float s = 0.f;
#pragma unroll
            for (int t = 0; t < 16; ++t) s += gp[t];
            inv_denom[tid] = 1.f / s;
        }
        // visibility via the K-loop's first __syncthreads
    }

    const uint16_t* gA[4];
    const uint16_t* gB[4];
    uint16_t* lA[4];
    uint16_t* lB[4];
#pragma unroll
    for (int c = 0; c < 4; ++c) {
        const int s   = (c * 4 + wave) * 64 + lane;
        const int r   = s >> 3;
        const int col = ((s & 7) ^ (r & 7)) * 8;
        gA[c] = A + (long long)(m0 + r) * lda + col;
        gB[c] = B + (long long)(n0 + r) * ldb + col;
        lA[c] = ldsA + (c * 4 + wave) * 512;
        lB[c] = ldsB + (c * 4 + wave) * 512;
    }

    const int m_off = (wave & 1) * 64;
    const int n_off = (wave >> 1) * 64;

    f32x4_t acc[4][4];
#pragma unroll
    for (int i = 0; i < 4; ++i)
#pragma unroll
        for (int j = 0; j < 4; ++j)
            acc[i][j] = f32x4_t{0.f, 0.f, 0.f, 0.f};

    for (int k0 = 0; k0 < K; k0 += 64) {
#pragma unroll
        for (int c = 0; c < 4; ++c) gload_lds16(gA[c], lA[c]);
#pragma unroll
        for (int c = 0; c < 4; ++c) gload_lds16(gB[c], lB[c]);
#pragma unroll
        for (int c = 0; c < 4; ++c) { gA[c] += 64; gB[c] += 64; }
        __syncthreads();

#pragma unroll
        for (int t = 0; t < 2; ++t) {
            const int csw = ((t * 4 + quad) ^ (l15 & 7)) * 8;
            bf16x8_t af[4], bfr[4];
#pragma unroll
            for (int i = 0; i < 4; ++i)
                af[i] = *(const bf16x8_t*)(ldsA + (m_off + i * 16 + l15) * 64 + csw);
#pragma unroll
            for (int j = 0; j < 4; ++j)
                bfr[j] = *(const bf16x8_t*)(ldsB + (n_off + j * 16 + l15) * 64 + csw);
#pragma unroll
            for (int i = 0; i < 4; ++i)
#pragma unroll
                for (int j = 0; j < 4; ++j)
                    acc[i][j] = __builtin_amdgcn_mfma_f32_16x16x32_bf16(af[i], bfr[j], acc[i][j], 0, 0, 0);
        }
        __syncthreads();
    }

    if (EPI == 3) {
        // e = exp2(acc*alpha); |s/32| small enough that no max-sub is needed.
        float rs[4][4];
#pragma unroll
        for (int i = 0; i < 4; ++i)
#pragma unroll
            for (int r = 0; r < 4; ++r) rs[i][r] = 0.f;
#pragma unroll
        for (int i = 0; i < 4; ++i) {
            const int mb = m0 + m_off + i * 16 + quad * 4;
#pragma unroll
            for (int j = 0; j < 4; ++j) {
                const int n = n0 + n_off + j * 16 + l15;
#pragma unroll
                for (int r = 0; r < 4; ++r) {
                    const float e = exp2f(acc[i][j][r] * alpha);
                    rs[i][r] += e;
                    ((uint16_t*)C)[(long long)(mb + r) * ldc + n] = f2bf(e);
                }
            }
        }
#pragma unroll
        for (int m = 1; m < 16; m <<= 1)
#pragma unroll
            for (int i = 0; i < 4; ++i)
#pragma unroll
                for (int r = 0; r < 4; ++r)
                    rs[i][r] += __shfl_xor(rs[i][r], m);
        float* lp = (float*)ldsA;   // reuse past last barrier: [4 waves][64 rows]
        if (l15 == 0) {
#pragma unroll
            for (int i = 0; i < 4; ++i)
#pragma unroll
                for (int r = 0; r < 4; ++r)
                    lp[wave * 64 + i * 16 + quad * 4 + r] = rs[i][r];
        }
        __syncthreads();
        if (tid < 128) {
            const float s = lp[(tid >> 6) * 64 + (tid & 63)] +
                            lp[((tid >> 6) + 2) * 64 + (tid & 63)];
            gsum[(long long)z * 32768 + (m0 + tid) * 16 + blockIdx.y] = s;
        }
    } else {  // EPI == 4
#pragma unroll
        for (int i = 0; i < 4; ++i) {
            const int rl = m_off + i * 16 + quad * 4;
            const int mb = m0 + rl;
#pragma unroll
            for (int j = 0; j < 4; ++j) {
                const int n = n0 + n_off + j * 16 + l15;
#pragma unroll
                for (int r = 0; r < 4; ++r)
                    ((float*)C)[(long long)(mb + r) * ldc + n] =
                        acc[i][j][r] * inv_denom[rl + r];
            }
        }
    }
}

// fp32 -> bf16 for x (blocks 0..8191) and Wq/Wk/Wv (blocks 8192..11263).
__global__ void cvt_all(const float* __restrict__ x,
                        const float* __restrict__ Wq, const float* __restrict__ Wk,
                        const float* __restrict__ Wv,
                        uint16_t* __restrict__ x_bf, uint16_t* __restrict__ w_bf) {
    const int b = blockIdx.x;
    const float* src;
    uint16_t* dst;
    int i;
    if (b < 8192) {
        src = x; dst = x_bf; i = b * 256 + threadIdx.x;
    } else {
        const int wz = (b - 8192) >> 10;
        const int rb = (b - 8192) & 1023;
        src = (wz == 0) ? Wq : (wz == 1) ? Wk : Wv;
        dst = w_bf + (long long)wz * 1048576;
        i = rb * 256 + threadIdx.x;
    }
    const float4 f = ((const float4*)src)[i];
    ushort4 o;
    o.x = f2bf(f.x); o.y = f2bf(f.y); o.z = f2bf(f.z); o.w = f2bf(f.w);
    ((ushort4*)dst)[i] = o;
}

extern "C" void kernel_launch(void* const* d_in, const int* in_sizes, int n_in,
                              void* d_out, int out_size, void* d_ws, size_t ws_size,
                              hipStream_t stream) {
    const float* x  = (const float*)d_in[0];
    const float* Wq = (const float*)d_in[1];
    const float* bq = (const float*)d_in[2];
    const float* Wk = (const float*)d_in[3];
    const float* bk = (const float*)d_in[4];
    const float* Wv = (const float*)d_in[5];
    const float* bv = (const float*)d_in[6];
    float* out = (float*)d_out;

    char* w = (char*)d_ws;
    uint16_t* x_bf = (uint16_t*)(w);
    float*    gsum = (float*)(w);                 // overlaps dead x_bf
    uint16_t* w_bf = (uint16_t*)(w + 16777216);
    uint16_t* Qb   = (uint16_t*)(w + 23068672);
    uint16_t* Kb   = (uint16_t*)(w + 39845888);
    uint16_t* Vt   = (uint16_t*)(w + 56623104);
    uint16_t* Pb   = (uint16_t*)(w + 73400320);

    // 1) fp32 -> bf16 conversions (x + all three W)
    cvt_all<<<11264, 256, 0, stream>>>(x, Wq, Wk, Wv, x_bf, w_bf);

    // 2) Q, K, Vt in ONE dispatch (grid 64x8x3, 1536 tiles)
    proj_qkv<<<dim3(64, 8, 3), 256, 0, stream>>>(
        x_bf, w_bf, bq, bk, bv, Qb, Kb, Vt);

    // 3) P~_b = exp((Q_b K_b^T)/32)  [2048,2048]/batch, bf16 + row-sum partials.
    //    alpha = (1/32)*log2(e).
    gemm_bt<3, uint16_t><<<dim3(16, 16, 4), 256, 0, stream>>>(
        Qb, 1024, 2097152LL,
        Kb, 1024, 2097152LL,
        Pb, 2048, 4194304LL,
        gsum, 1024, 0.045084222f);

    // 4) O_b = (P~_b @ V_b) / denom : fp32 out
    gemm_bt<4, float><<<dim3(16, 8, 4), 256, 0, stream>>>(
        Pb, 2048, 4194304LL,
        Vt, 8192, 2048LL,
        out, 1024, 2097152LL,
        gsum, 2048, 1.0f);
}

// Round 7
// 234.276 us; speedup vs baseline: 1.0898x; 1.0898x over previous
//
#include <hip/hip_runtime.h>
#include <cstdint>

// B=4, S=2048, D=1024.  M_qkv = B*S = 8192.
// ws layout (bytes):
//   x_bf  @ 0        : 16,777,216  bf16 [8192][1024] (dead after Vt-proj;
//                      gsum f32[8192][16] overlays @0, written by score)
//   w_bf  @ 16777216 :  6,291,456  bf16 Wq,Wk,Wv each [1024][1024]
//   Qf8   @ 23068672 :  8,388,608  fp8 e4m3 [8192][1024]
//   Kf8   @ 31457280 :  8,388,608  fp8 e4m3 [8192][1024]
//   Vt    @ 39845888 : 16,777,216  bf16 [1024][8192], col = b*2048+s
//   P~    @ 56623104 : 33,554,432  bf16 [4][2048][2048] = exp(s/32), unnorm.
// total ~90 MB

typedef __bf16 bf16x8_t __attribute__((ext_vector_type(8)));
typedef float  f32x4_t  __attribute__((ext_vector_type(4)));
typedef int    i32x8_t  __attribute__((ext_vector_type(8)));
typedef int    i32x4_t  __attribute__((ext_vector_type(4)));

__device__ __forceinline__ uint16_t f2bf(float f) {
    union { float f; uint32_t u; } v; v.f = f;
    return (uint16_t)((v.u + 0x7fffu + ((v.u >> 16) & 1u)) >> 16);  // RNE
}

// fp32 -> OCP e4m3fn, RNE.  Values here are |f| <~ 8, well inside range.
__device__ __forceinline__ uint8_t f2fp8(float f) {
    union { float f; uint32_t u; } v; v.f = f;
    const uint32_t sgn = (v.u >> 31) << 7;
    const uint32_t mag = v.u & 0x7fffffffu;
    uint32_t out;
    if (mag < 0x3c800000u) {                       // |f| < 2^-6: subnormal
        out = (uint32_t)__builtin_rintf(__builtin_fabsf(f) * 512.0f); // 0..8
    } else {
        uint32_t t = mag + 0x7ffffu + ((mag >> 20) & 1u);  // RNE at bit 20
        out = (t >> 20) - 960u;                            // (E<<3|m) - (120<<3)
        if (out > 0x7eu) out = 0x7eu;                      // clamp to 448
    }
    return (uint8_t)(sgn | out);
}

__device__ __forceinline__ void gload_lds16(const void* g, void* lds) {
    __builtin_amdgcn_global_load_lds(
        (const __attribute__((address_space(1))) void*)g,
        (__attribute__((address_space(3))) void*)lds, 16, 0, 0);
}

// ---------------------------------------------------------------------------
// bf16 B^T GEMM, 128x128/BK=64, XOR-swizzled LDS (r5-proven).
// EPI: 1 = +bias[n], fp8 out (Q/K proj -> fp8 score inputs)
//      2 = +bias[m], bf16 out (Vt proj)
//      4 = acc * (1/sum16(gsum_row)) fp32 out (PV)
// ---------------------------------------------------------------------------
template <int EPI, typename OutT>
__global__ __launch_bounds__(256, 4) void gemm_bt(
    const uint16_t* __restrict__ A, int lda, long long sAz,
    const uint16_t* __restrict__ B, int ldb, long long sBz,
    OutT* __restrict__ C, int ldc, long long sCz,
    const float* __restrict__ bias0, const float* __restrict__ bias1,
    float* __restrict__ gsum, int K, float alpha)
{
    __shared__ uint16_t ldsA[128 * 64];
    __shared__ uint16_t ldsB[128 * 64];
    __shared__ float inv_denom[128];

    const int tid  = threadIdx.x;
    const int wave = tid >> 6;
    const int lane = tid & 63;
    const int quad = lane >> 4;
    const int l15  = lane & 15;
    const int z    = blockIdx.z;

    A += (long long)z * sAz;
    B += (long long)z * sBz;
    C += (long long)z * sCz;

    const int m0 = blockIdx.x * 128;
    const int n0 = blockIdx.y * 128;

    if (EPI == 4) {
        if (tid < 128) {
            const float* gp = gsum + (long long)z * 32768 + (m0 + tid) * 16;
            float s = 0.f;
#pragma unroll
            for (int t = 0; t < 16; ++t) s += gp[t];
            inv_denom[tid] = 1.f / s;
        }
        // visibility via the K-loop's first __syncthreads
    }

    const uint16_t* gA[4];
    const uint16_t* gB[4];
    uint16_t* lA[4];
    uint16_t* lB[4];
#pragma unroll
    for (int c = 0; c < 4; ++c) {
        const int s   = (c * 4 + wave) * 64 + lane;
        const int r   = s >> 3;
        const int col = ((s & 7) ^ (r & 7)) * 8;
        gA[c] = A + (long long)(m0 + r) * lda + col;
        gB[c] = B + (long long)(n0 + r) * ldb + col;
        lA[c] = ldsA + (c * 4 + wave) * 512;   // wave-uniform base
        lB[c] = ldsB + (c * 4 + wave) * 512;
    }

    const int m_off = (wave & 1) * 64;
    const int n_off = (wave >> 1) * 64;

    f32x4_t acc[4][4];
#pragma unroll
    for (int i = 0; i < 4; ++i)
#pragma unroll
        for (int j = 0; j < 4; ++j)
            acc[i][j] = f32x4_t{0.f, 0.f, 0.f, 0.f};

    for (int k0 = 0; k0 < K; k0 += 64) {
#pragma unroll
        for (int c = 0; c < 4; ++c) gload_lds16(gA[c], lA[c]);
#pragma unroll
        for (int c = 0; c < 4; ++c) gload_lds16(gB[c], lB[c]);
#pragma unroll
        for (int c = 0; c < 4; ++c) { gA[c] += 64; gB[c] += 64; }
        __syncthreads();

#pragma unroll
        for (int t = 0; t < 2; ++t) {
            const int csw = ((t * 4 + quad) ^ (l15 & 7)) * 8;
            bf16x8_t af[4], bfr[4];
#pragma unroll
            for (int i = 0; i < 4; ++i)
                af[i] = *(const bf16x8_t*)(ldsA + (m_off + i * 16 + l15) * 64 + csw);
#pragma unroll
            for (int j = 0; j < 4; ++j)
                bfr[j] = *(const bf16x8_t*)(ldsB + (n_off + j * 16 + l15) * 64 + csw);
#pragma unroll
            for (int i = 0; i < 4; ++i)
#pragma unroll
                for (int j = 0; j < 4; ++j)
                    acc[i][j] = __builtin_amdgcn_mfma_f32_16x16x32_bf16(af[i], bfr[j], acc[i][j], 0, 0, 0);
        }
        __syncthreads();
    }

    if (EPI == 1 || EPI == 2) {
        const float* bias = (z == 0) ? bias0 : bias1;
#pragma unroll
        for (int i = 0; i < 4; ++i) {
            const int mb = m0 + m_off + i * 16 + quad * 4;
            float rb[4];
            if (EPI == 2) {
#pragma unroll
                for (int r = 0; r < 4; ++r) rb[r] = bias[mb + r];
            }
#pragma unroll
            for (int j = 0; j < 4; ++j) {
                const int n = n0 + n_off + j * 16 + l15;
                const float cb = (EPI == 1) ? bias[n] : 0.f;
#pragma unroll
                for (int r = 0; r < 4; ++r) {
                    const float v = acc[i][j][r] + ((EPI == 1) ? cb : rb[r]);
                    if (sizeof(OutT) == 1)
                        ((uint8_t*)C)[(long long)(mb + r) * ldc + n] = f2fp8(v);
                    else
                        ((uint16_t*)C)[(long long)(mb + r) * ldc + n] = f2bf(v);
                }
            }
        }
    } else {  // EPI == 4
#pragma unroll
        for (int i = 0; i < 4; ++i) {
            const int rl = m_off + i * 16 + quad * 4;
            const int mb = m0 + rl;
#pragma unroll
            for (int j = 0; j < 4; ++j) {
                const int n = n0 + n_off + j * 16 + l15;
#pragma unroll
                for (int r = 0; r < 4; ++r)
                    ((float*)C)[(long long)(mb + r) * ldc + n] =
                        acc[i][j][r] * inv_denom[rl + r];
            }
        }
    }
}

// ---------------------------------------------------------------------------
// fp8 score GEMM: P~ = exp((Q K^T)/32), MX-fp8 MFMA K=128 with unit scales.
// Tile 128x128, BK=128 fp8 (128 B/row — byte-identical LDS layout + XOR
// swizzle as the bf16 kernel).  C/D layout is shape-determined (16x16), so
// the EPI-3 epilogue is the r5-verified code verbatim.
// ---------------------------------------------------------------------------
__global__ __launch_bounds__(256, 3) void score_f8(
    const uint8_t* __restrict__ Qf8, const uint8_t* __restrict__ Kf8,
    uint16_t* __restrict__ P, float* __restrict__ gsum, float alpha)
{
    __shared__ uint8_t ldsA[128 * 128];
    __shared__ uint8_t ldsB[128 * 128];

    const int tid  = threadIdx.x;
    const int wave = tid >> 6;
    const int lane = tid & 63;
    const int quad = lane >> 4;
    const int l15  = lane & 15;
    const int z    = blockIdx.z;

    const uint8_t* A = Qf8 + (long long)z * 2097152;
    const uint8_t* B = Kf8 + (long long)z * 2097152;
    uint16_t* C = P + (long long)z * 4194304;

    const int m0 = blockIdx.x * 128;
    const int n0 = blockIdx.y * 128;

    // staging: 1024 16B slots/side; slot s -> row r=s>>3, holds global chunk
    // (s&7)^(r&7) (16 fp8 k's per chunk, 8 chunks = 128 k per row).
    const uint8_t* gA[4];
    const uint8_t* gB[4];
    uint8_t* lA[4];
    uint8_t* lB[4];
#pragma unroll
    for (int c = 0; c < 4; ++c) {
        const int s   = (c * 4 + wave) * 64 + lane;
        const int r   = s >> 3;
        const int col = ((s & 7) ^ (r & 7)) * 16;
        gA[c] = A + (long long)(m0 + r) * 1024 + col;
        gB[c] = B + (long long)(n0 + r) * 1024 + col;
        lA[c] = ldsA + (c * 4 + wave) * 1024;   // wave-uniform base
        lB[c] = ldsB + (c * 4 + wave) * 1024;
    }

    const int m_off = (wave & 1) * 64;
    const int n_off = (wave >> 1) * 64;

    f32x4_t acc[4][4];
#pragma unroll
    for (int i = 0; i < 4; ++i)
#pragma unroll
        for (int j = 0; j < 4; ++j)
            acc[i][j] = f32x4_t{0.f, 0.f, 0.f, 0.f};

    // frag k = quad*32 + j (j 0..31): global chunks 2q (k 32q..+15) and
    // 2q+1 (k 32q+16..+31), swizzle-relocated independently.
    const int h0 = quad * 2;
    const int h1 = quad * 2 + 1;

    for (int k0 = 0; k0 < 1024; k0 += 128) {
#pragma unroll
        for (int c = 0; c < 4; ++c) gload_lds16(gA[c], lA[c]);
#pragma unroll
        for (int c = 0; c < 4; ++c) gload_lds16(gB[c], lB[c]);
#pragma unroll
        for (int c = 0; c < 4; ++c) { gA[c] += 128; gB[c] += 128; }
        __syncthreads();

        i32x8_t af[4], bfr[4];
#pragma unroll
        for (int i = 0; i < 4; ++i) {
            const int m = m_off + i * 16 + l15;
            const int sw = m & 7;
            const i32x4_t lo = *(const i32x4_t*)(ldsA + m * 128 + (h0 ^ sw) * 16);
            const i32x4_t hi = *(const i32x4_t*)(ldsA + m * 128 + (h1 ^ sw) * 16);
            af[i] = i32x8_t{lo[0], lo[1], lo[2], lo[3], hi[0], hi[1], hi[2], hi[3]};
        }
#pragma unroll
        for (int j = 0; j < 4; ++j) {
            const int n = n_off + j * 16 + l15;
            const int sw = n & 7;
            const i32x4_t lo = *(const i32x4_t*)(ldsB + n * 128 + (h0 ^ sw) * 16);
            const i32x4_t hi = *(const i32x4_t*)(ldsB + n * 128 + (h1 ^ sw) * 16);
            bfr[j] = i32x8_t{lo[0], lo[1], lo[2], lo[3], hi[0], hi[1], hi[2], hi[3]};
        }
#pragma unroll
        for (int i = 0; i < 4; ++i)
#pragma unroll
            for (int j = 0; j < 4; ++j)
                acc[i][j] = __builtin_amdgcn_mfma_scale_f32_16x16x128_f8f6f4(
                    af[i], bfr[j], acc[i][j],
                    0, 0,                       // cbsz, blgp: fp8 e4m3 / fp8 e4m3
                    0, 0x7f7f7f7f,              // opsel_a, scale_a (e8m0 127 = x1)
                    0, 0x7f7f7f7f);             // opsel_b, scale_b
        __syncthreads();
    }

    // EPI-3 epilogue (r5-verified, C/D layout shape-determined).
    float rs[4][4];
#pragma unroll
    for (int i = 0; i < 4; ++i)
#pragma unroll
        for (int r = 0; r < 4; ++r) rs[i][r] = 0.f;
#pragma unroll
    for (int i = 0; i < 4; ++i) {
        const int mb = m0 + m_off + i * 16 + quad * 4;
#pragma unroll
        for (int j = 0; j < 4; ++j) {
            const int n = n0 + n_off + j * 16 + l15;
#pragma unroll
            for (int r = 0; r < 4; ++r) {
                const float e = exp2f(acc[i][j][r] * alpha);
                rs[i][r] += e;
                C[(long long)(mb + r) * 2048 + n] = f2bf(e);
            }
        }
    }
#pragma unroll
    for (int m = 1; m < 16; m <<= 1)
#pragma unroll
        for (int i = 0; i < 4; ++i)
#pragma unroll
            for (int r = 0; r < 4; ++r)
                rs[i][r] += __shfl_xor(rs[i][r], m);
    float* lp = (float*)ldsA;   // reuse past last barrier: [4 waves][64 rows]
    if (l15 == 0) {
#pragma unroll
        for (int i = 0; i < 4; ++i)
#pragma unroll
            for (int r = 0; r < 4; ++r)
                lp[wave * 64 + i * 16 + quad * 4 + r] = rs[i][r];
    }
    __syncthreads();
    if (tid < 128) {
        const float s = lp[(tid >> 6) * 64 + (tid & 63)] +
                        lp[((tid >> 6) + 2) * 64 + (tid & 63)];
        gsum[(long long)z * 32768 + (m0 + tid) * 16 + blockIdx.y] = s;
    }
}

// fp32 -> bf16 for x (blocks 0..8191) and Wq/Wk/Wv (blocks 8192..11263).
__global__ void cvt_all(const float* __restrict__ x,
                        const float* __restrict__ Wq, const float* __restrict__ Wk,
                        const float* __restrict__ Wv,
                        uint16_t* __restrict__ x_bf, uint16_t* __restrict__ w_bf) {
    const int b = blockIdx.x;
    const float* src;
    uint16_t* dst;
    int i;
    if (b < 8192) {
        src = x; dst = x_bf; i = b * 256 + threadIdx.x;
    } else {
        const int wz = (b - 8192) >> 10;
        const int rb = (b - 8192) & 1023;
        src = (wz == 0) ? Wq : (wz == 1) ? Wk : Wv;
        dst = w_bf + (long long)wz * 1048576;
        i = rb * 256 + threadIdx.x;
    }
    const float4 f = ((const float4*)src)[i];
    ushort4 o;
    o.x = f2bf(f.x); o.y = f2bf(f.y); o.z = f2bf(f.z); o.w = f2bf(f.w);
    ((ushort4*)dst)[i] = o;
}

extern "C" void kernel_launch(void* const* d_in, const int* in_sizes, int n_in,
                              void* d_out, int out_size, void* d_ws, size_t ws_size,
                              hipStream_t stream) {
    const float* x  = (const float*)d_in[0];
    const float* Wq = (const float*)d_in[1];
    const float* bq = (const float*)d_in[2];
    const float* Wk = (const float*)d_in[3];
    const float* bk = (const float*)d_in[4];
    const float* Wv = (const float*)d_in[5];
    const float* bv = (const float*)d_in[6];
    float* out = (float*)d_out;

    char* w = (char*)d_ws;
    uint16_t* x_bf = (uint16_t*)(w);
    float*    gsum = (float*)(w);                 // overlays dead x_bf
    uint16_t* w_bf = (uint16_t*)(w + 16777216);
    uint8_t*  Qf8  = (uint8_t*)(w + 23068672);
    uint8_t*  Kf8  = (uint8_t*)(w + 31457280);
    uint16_t* Vt   = (uint16_t*)(w + 39845888);
    uint16_t* Pb   = (uint16_t*)(w + 56623104);

    // 1) fp32 -> bf16 conversions (x + all three W)
    cvt_all<<<11264, 256, 0, stream>>>(x, Wq, Wk, Wv, x_bf, w_bf);

    // 2) Q,K = x @ W^T + b   [8192,1024], stored fp8 e4m3 for the score GEMM
    gemm_bt<1, uint8_t><<<dim3(64, 8, 2), 256, 0, stream>>>(
        x_bf, 1024, 0LL,
        w_bf, 1024, 1048576LL,
        Qf8, 1024, 8388608LL,
        bq, bk, nullptr, 1024, 1.0f);

    // 2b) Vt[e, b*2048+s] = sum_d Wv[e,d]*x[s,d] + bv[e]  [1024,8192], row bias
    gemm_bt<2, uint16_t><<<dim3(8, 64, 1), 256, 0, stream>>>(
        w_bf + 2097152, 1024, 0LL,
        x_bf, 1024, 0LL,
        Vt, 8192, 0LL,
        bv, bv, nullptr, 1024, 1.0f);

    // 3) P~_b = exp((Q_b K_b^T)/32) via MX-fp8 K=128; alpha = (1/32)*log2(e)
    score_f8<<<dim3(16, 16, 4), 256, 0, stream>>>(
        Qf8, Kf8, Pb, gsum, 0.045084222f);

    // 4) O_b = (P~_b @ V_b) / denom : fp32 out
    gemm_bt<4, float><<<dim3(16, 8, 4), 256, 0, stream>>>(
        Pb, 2048, 4194304LL,
        Vt, 8192, 2048LL,
        out, 1024, 2097152LL,
        nullptr, nullptr, gsum, 2048, 1.0f);
}